// Round 1
// baseline (1916.863 us; speedup 1.0000x reference)
//
#include <hip/hip_runtime.h>

// ---------------------------------------------------------------------------
// GNN forward: h = x@W_in + b; 4x message-passing layers; mean-pool; predict.
// Decomposition: per-edge message relu([h_s,h_d,e]@Wm + b)
//   == relu(A[src] + B[dst] + e@Wm3), with A = h@Wm1, B = h@Wm2 + b.
// ---------------------------------------------------------------------------

#define THREADS 256

// C[M x 128] = X[M x K] @ W[K x 128]  (+bias) (opt relu) (opt residual add)
// K = 128 (X1 only) or 256 (k<128 from X1, k>=128 from X2). Row stride 128.
template<bool RELU, bool RESID>
__global__ __launch_bounds__(THREADS)
void gemm_tile(const float* __restrict__ X1, const float* __restrict__ X2,
               const float* __restrict__ W, const float* __restrict__ bias,
               const float* __restrict__ resid, float* __restrict__ C,
               int M, int K)
{
    __shared__ float XsT[16][68];   // transposed X tile [k][m], padded
    __shared__ float Ws[16][128];   // W tile [k][n]

    const int t   = threadIdx.x;
    const int c0  = (t & 31) * 4;   // output cols c0..c0+3
    const int r0  = (t >> 5) * 8;   // output rows r0..r0+7 (within tile)
    const int mBase = blockIdx.x * 64;

    float acc[8][4];
#pragma unroll
    for (int i = 0; i < 8; i++)
#pragma unroll
        for (int j = 0; j < 4; j++) acc[i][j] = 0.f;

    const int sm = t >> 2;          // staging row 0..63
    const int sk = (t & 3) * 4;     // staging k quad
    const int gm = mBase + sm;
    const int wr0 = t >> 5;         // W staging row 0..7
    const int wc0 = (t & 31) * 4;

    for (int k0 = 0; k0 < K; k0 += 16) {
        const float* Xsrc = X1;
        int koff = k0;
        if (k0 >= 128) { Xsrc = X2; koff = k0 - 128; }

        float4 xv;
        if (gm < M) xv = *reinterpret_cast<const float4*>(Xsrc + (size_t)gm * 128 + koff + sk);
        else        xv = make_float4(0.f, 0.f, 0.f, 0.f);

        float4 wv0 = *reinterpret_cast<const float4*>(W + (size_t)(k0 + wr0) * 128 + wc0);
        float4 wv1 = *reinterpret_cast<const float4*>(W + (size_t)(k0 + wr0 + 8) * 128 + wc0);

        __syncthreads();  // previous iteration's consumers done

        XsT[sk + 0][sm] = xv.x;
        XsT[sk + 1][sm] = xv.y;
        XsT[sk + 2][sm] = xv.z;
        XsT[sk + 3][sm] = xv.w;
        *reinterpret_cast<float4*>(&Ws[wr0][wc0])     = wv0;
        *reinterpret_cast<float4*>(&Ws[wr0 + 8][wc0]) = wv1;

        __syncthreads();

#pragma unroll
        for (int kk = 0; kk < 16; kk++) {
            float4 wv = *reinterpret_cast<const float4*>(&Ws[kk][c0]);
            float4 xa = *reinterpret_cast<const float4*>(&XsT[kk][r0]);
            float4 xb = *reinterpret_cast<const float4*>(&XsT[kk][r0 + 4]);
            float xr[8] = {xa.x, xa.y, xa.z, xa.w, xb.x, xb.y, xb.z, xb.w};
#pragma unroll
            for (int i = 0; i < 8; i++) {
                acc[i][0] = fmaf(xr[i], wv.x, acc[i][0]);
                acc[i][1] = fmaf(xr[i], wv.y, acc[i][1]);
                acc[i][2] = fmaf(xr[i], wv.z, acc[i][2]);
                acc[i][3] = fmaf(xr[i], wv.w, acc[i][3]);
            }
        }
    }

#pragma unroll
    for (int i = 0; i < 8; i++) {
        int gr = mBase + r0 + i;
        if (gr >= M) continue;
        float4 v;
        v.x = acc[i][0]; v.y = acc[i][1]; v.z = acc[i][2]; v.w = acc[i][3];
        if (bias) {
            v.x += bias[c0 + 0]; v.y += bias[c0 + 1];
            v.z += bias[c0 + 2]; v.w += bias[c0 + 3];
        }
        if (RELU) {
            v.x = fmaxf(v.x, 0.f); v.y = fmaxf(v.y, 0.f);
            v.z = fmaxf(v.z, 0.f); v.w = fmaxf(v.w, 0.f);
        }
        if (RESID) {
            float4 rv = *reinterpret_cast<const float4*>(resid + (size_t)gr * 128 + c0);
            v.x += rv.x; v.y += rv.y; v.z += rv.z; v.w += rv.w;
        }
        *reinterpret_cast<float4*>(C + (size_t)gr * 128 + c0) = v;
    }
}

__global__ __launch_bounds__(THREADS)
void zero_f32(float* __restrict__ p, int n4)
{
    int i = blockIdx.x * blockDim.x + threadIdx.x;
    int stride = gridDim.x * blockDim.x;
    float4 z = make_float4(0.f, 0.f, 0.f, 0.f);
    for (; i < n4; i += stride) reinterpret_cast<float4*>(p)[i] = z;
}

// Per-edge: v = relu(A[src] + B[dst] + e @ Wm3); atomicAdd into agg[dst].
// 16 edges per block; thread = (edge pair selector, channel).
__global__ __launch_bounds__(THREADS)
void edge_msg(const float* __restrict__ A, const float* __restrict__ Bb,
              const float* __restrict__ eattr, const int* __restrict__ esrc,
              const int* __restrict__ edst, const float* __restrict__ Wm3,
              float* __restrict__ agg, int nE)
{
    __shared__ float W3[16 * 128];
    __shared__ float ea[16][16];
    __shared__ int   sd[2][16];

    const int t  = threadIdx.x;
    const int e0 = blockIdx.x * 16;

    // stage Wm3 (16x128)
    *reinterpret_cast<float4*>(&W3[t * 4])            = *reinterpret_cast<const float4*>(Wm3 + t * 4);
    *reinterpret_cast<float4*>(&W3[(t + 256) * 4])    = *reinterpret_cast<const float4*>(Wm3 + (t + 256) * 4);
    // stage edge attrs (16 edges x 16)
    {
        int e = e0 + (t >> 4);
        ea[t >> 4][t & 15] = (e < nE) ? eattr[(size_t)e0 * 16 + t] : 0.f;
    }
    if (t < 16)       sd[0][t]      = (e0 + t < nE)      ? esrc[e0 + t]      : 0;
    else if (t < 32)  sd[1][t - 16] = (e0 + t - 16 < nE) ? edst[e0 + t - 16] : 0;
    __syncthreads();

    const int c    = t & 127;
    const int half = t >> 7;
#pragma unroll
    for (int i = 0; i < 8; i++) {
        int j = i * 2 + half;
        if (e0 + j >= nE) continue;
        int s = sd[0][j];
        int d = sd[1][j];
        float v = A[(size_t)s * 128 + c] + Bb[(size_t)d * 128 + c];
#pragma unroll
        for (int k = 0; k < 16; k++) v = fmaf(ea[j][k], W3[k * 128 + c], v);
        v = fmaxf(v, 0.f);
        atomicAdd(&agg[(size_t)d * 128 + c], v);
    }
}

// Per-graph mean pool over sorted `batch`, then dot with W_pred.
__global__ __launch_bounds__(THREADS)
void pool_pred(const float* __restrict__ h, const int* __restrict__ batch,
               const float* __restrict__ Wp, const float* __restrict__ bp,
               float* __restrict__ out, int n)
{
    __shared__ float red[THREADS];
    const int g = blockIdx.x;
    const int t = threadIdx.x;

    int lo, hi;
    {
        int a = 0, b = n;
        while (a < b) { int m = (a + b) >> 1; if (batch[m] < g) a = m + 1; else b = m; }
        lo = a;
        b = n;
        while (a < b) { int m = (a + b) >> 1; if (batch[m] < g + 1) a = m + 1; else b = m; }
        hi = a;
    }
    const int cnt  = hi - lo;
    const int c    = t & 127;
    const int half = t >> 7;

    float s = 0.f;
    for (int i = lo + half; i < hi; i += 2) s += h[(size_t)i * 128 + c];
    red[t] = s;
    __syncthreads();

    if (t < 128) {
        float mean = (red[t] + red[t + 128]) / (float)max(cnt, 1);
        red[t] = mean * Wp[c];
    }
    __syncthreads();
    for (int off = 64; off > 0; off >>= 1) {
        if (t < off) red[t] += red[t + off];
        __syncthreads();
    }
    if (t == 0) out[g] = red[0] + bp[0];
}

extern "C" void kernel_launch(void* const* d_in, const int* in_sizes, int n_in,
                              void* d_out, int out_size, void* d_ws, size_t ws_size,
                              hipStream_t stream)
{
    const float* x      = (const float*)d_in[0];
    const int*   ei     = (const int*)  d_in[1];
    const float* eattr  = (const float*)d_in[2];
    const int*   batch  = (const int*)  d_in[3];
    const float* W_in   = (const float*)d_in[4];
    const float* b_in   = (const float*)d_in[5];
    const float* W_msg  = (const float*)d_in[6];
    const float* b_msg  = (const float*)d_in[7];
    const float* W_upd  = (const float*)d_in[8];
    const float* b_upd  = (const float*)d_in[9];
    const float* W_pred = (const float*)d_in[10];
    const float* b_pred = (const float*)d_in[11];
    float* out = (float*)d_out;

    const int nN = in_sizes[0] / 128;   // 50000
    const int nE = in_sizes[1] / 2;     // 800000

    float* h   = (float*)d_ws;
    float* A   = h  + (size_t)nN * 128;
    float* Bb  = A  + (size_t)nN * 128;
    float* agg = Bb + (size_t)nN * 128;

    dim3 blk(THREADS);
    const int gx = (nN + 63) / 64;

    // h = x @ W_in + b_in
    gemm_tile<false, false><<<gx, blk, 0, stream>>>(x, nullptr, W_in, b_in, nullptr, h, nN, 128);

    for (int l = 0; l < 4; l++) {
        const float* Wm = W_msg + (size_t)l * 272 * 128;
        const float* bm = b_msg + l * 128;
        const float* Wu = W_upd + (size_t)l * 256 * 128;
        const float* bu = b_upd + l * 128;

        // A = h @ Wm1 ; B = h @ Wm2 + b_msg
        gemm_tile<false, false><<<gx, blk, 0, stream>>>(h, nullptr, Wm,             nullptr, nullptr, A,  nN, 128);
        gemm_tile<false, false><<<gx, blk, 0, stream>>>(h, nullptr, Wm + 128 * 128, bm,      nullptr, Bb, nN, 128);

        zero_f32<<<1024, blk, 0, stream>>>(agg, nN * 128 / 4);
        edge_msg<<<(nE + 15) / 16, blk, 0, stream>>>(A, Bb, eattr, ei, ei + nE, Wm + 256 * 128, agg, nE);

        // h = h + relu([h, agg] @ W_upd + b_upd)   (in-place safe: blocks own rows)
        gemm_tile<true, true><<<gx, blk, 0, stream>>>(h, agg, Wu, bu, h, h, nN, 256);
    }

    pool_pred<<<64, blk, 0, stream>>>(h, batch, W_pred, b_pred, out, nN);
}

// Round 2
// 1203.206 us; speedup vs baseline: 1.5931x; 1.5931x over previous
//
#include <hip/hip_runtime.h>

// ---------------------------------------------------------------------------
// GNN forward: h = x@W_in + b; 4x message-passing layers; mean-pool; predict.
// Decomposition: per-edge message relu([h_s,h_d,e]@Wm + b)
//   == relu(A[src] + B[dst] + e@Wm3), with A = h@Wm1, B = h@Wm2 + b.
// Graph is layer-invariant -> build CSR (by dst) once, aggregate atomically-free.
// ---------------------------------------------------------------------------

#define THREADS 256

// C[M x 128] = X[M x K] @ W[K x 128]  (+bias) (opt relu) (opt residual add)
// K = 128 (X1 only) or 256 (k<128 from X1, k>=128 from X2). Row stride 128.
template<bool RELU, bool RESID>
__global__ __launch_bounds__(THREADS)
void gemm_tile(const float* __restrict__ X1, const float* __restrict__ X2,
               const float* __restrict__ W, const float* __restrict__ bias,
               const float* __restrict__ resid, float* __restrict__ C,
               int M, int K)
{
    __shared__ float XsT[16][68];   // transposed X tile [k][m], padded
    __shared__ float Ws[16][128];   // W tile [k][n]

    const int t   = threadIdx.x;
    const int c0  = (t & 31) * 4;   // output cols c0..c0+3
    const int r0  = (t >> 5) * 8;   // output rows r0..r0+7 (within tile)
    const int mBase = blockIdx.x * 64;

    float acc[8][4];
#pragma unroll
    for (int i = 0; i < 8; i++)
#pragma unroll
        for (int j = 0; j < 4; j++) acc[i][j] = 0.f;

    const int sm = t >> 2;          // staging row 0..63
    const int sk = (t & 3) * 4;     // staging k quad
    const int gm = mBase + sm;
    const int wr0 = t >> 5;         // W staging row 0..7
    const int wc0 = (t & 31) * 4;

    for (int k0 = 0; k0 < K; k0 += 16) {
        const float* Xsrc = X1;
        int koff = k0;
        if (k0 >= 128) { Xsrc = X2; koff = k0 - 128; }

        float4 xv;
        if (gm < M) xv = *reinterpret_cast<const float4*>(Xsrc + (size_t)gm * 128 + koff + sk);
        else        xv = make_float4(0.f, 0.f, 0.f, 0.f);

        float4 wv0 = *reinterpret_cast<const float4*>(W + (size_t)(k0 + wr0) * 128 + wc0);
        float4 wv1 = *reinterpret_cast<const float4*>(W + (size_t)(k0 + wr0 + 8) * 128 + wc0);

        __syncthreads();  // previous iteration's consumers done

        XsT[sk + 0][sm] = xv.x;
        XsT[sk + 1][sm] = xv.y;
        XsT[sk + 2][sm] = xv.z;
        XsT[sk + 3][sm] = xv.w;
        *reinterpret_cast<float4*>(&Ws[wr0][wc0])     = wv0;
        *reinterpret_cast<float4*>(&Ws[wr0 + 8][wc0]) = wv1;

        __syncthreads();

#pragma unroll
        for (int kk = 0; kk < 16; kk++) {
            float4 wv = *reinterpret_cast<const float4*>(&Ws[kk][c0]);
            float4 xa = *reinterpret_cast<const float4*>(&XsT[kk][r0]);
            float4 xb = *reinterpret_cast<const float4*>(&XsT[kk][r0 + 4]);
            float xr[8] = {xa.x, xa.y, xa.z, xa.w, xb.x, xb.y, xb.z, xb.w};
#pragma unroll
            for (int i = 0; i < 8; i++) {
                acc[i][0] = fmaf(xr[i], wv.x, acc[i][0]);
                acc[i][1] = fmaf(xr[i], wv.y, acc[i][1]);
                acc[i][2] = fmaf(xr[i], wv.z, acc[i][2]);
                acc[i][3] = fmaf(xr[i], wv.w, acc[i][3]);
            }
        }
    }

#pragma unroll
    for (int i = 0; i < 8; i++) {
        int gr = mBase + r0 + i;
        if (gr >= M) continue;
        float4 v;
        v.x = acc[i][0]; v.y = acc[i][1]; v.z = acc[i][2]; v.w = acc[i][3];
        if (bias) {
            v.x += bias[c0 + 0]; v.y += bias[c0 + 1];
            v.z += bias[c0 + 2]; v.w += bias[c0 + 3];
        }
        if (RELU) {
            v.x = fmaxf(v.x, 0.f); v.y = fmaxf(v.y, 0.f);
            v.z = fmaxf(v.z, 0.f); v.w = fmaxf(v.w, 0.f);
        }
        if (RESID) {
            float4 rv = *reinterpret_cast<const float4*>(resid + (size_t)gr * 128 + c0);
            v.x += rv.x; v.y += rv.y; v.z += rv.z; v.w += rv.w;
        }
        *reinterpret_cast<float4*>(C + (size_t)gr * 128 + c0) = v;
    }
}

__global__ __launch_bounds__(THREADS)
void zero_i32(int* __restrict__ p, int n)
{
    int i = blockIdx.x * blockDim.x + threadIdx.x;
    int stride = gridDim.x * blockDim.x;
    for (; i < n; i += stride) p[i] = 0;
}

// ---------------- CSR build (once per call; graph is layer-invariant) -------

__global__ __launch_bounds__(THREADS)
void csr_hist(const int* __restrict__ edst, int* __restrict__ deg, int nE)
{
    int i = blockIdx.x * blockDim.x + threadIdx.x;
    int stride = gridDim.x * blockDim.x;
    for (; i < nE; i += stride) atomicAdd(&deg[edst[i]], 1);
}

// single-block chunked inclusive scan -> rowptr (n+1 entries) and wp = rowptr[i]
__global__ __launch_bounds__(THREADS)
void csr_scan(const int* __restrict__ deg, int* __restrict__ rowptr,
              int* __restrict__ wp, int n)
{
    __shared__ int buf[THREADS];
    __shared__ int carry;
    const int t = threadIdx.x;
    if (t == 0) { carry = 0; rowptr[0] = 0; }
    __syncthreads();

    for (int base = 0; base < n; base += THREADS) {
        int v = (base + t < n) ? deg[base + t] : 0;
        buf[t] = v;
        __syncthreads();
#pragma unroll
        for (int off = 1; off < THREADS; off <<= 1) {
            int x = (t >= off) ? buf[t - off] : 0;
            __syncthreads();
            buf[t] += x;
            __syncthreads();
        }
        int incl = buf[t];
        if (base + t < n) {
            rowptr[base + t + 1] = carry + incl;
            wp[base + t]         = carry + incl - v;
        }
        __syncthreads();
        if (t == THREADS - 1) carry += buf[THREADS - 1];
        __syncthreads();
    }
}

// scatter edges into CSR order; permute edge_attr rows alongside
__global__ __launch_bounds__(THREADS)
void csr_scatter(const int* __restrict__ esrc, const int* __restrict__ edst,
                 const float* __restrict__ eattr, int* __restrict__ wp,
                 int* __restrict__ col, float* __restrict__ eattrp, int nE)
{
    int i = blockIdx.x * blockDim.x + threadIdx.x;
    int stride = gridDim.x * blockDim.x;
    for (; i < nE; i += stride) {
        int d = edst[i];
        int pos = atomicAdd(&wp[d], 1);
        col[pos] = esrc[i];
        const float4* src4 = reinterpret_cast<const float4*>(eattr + (size_t)i * 16);
        float4*       dst4 = reinterpret_cast<float4*>(eattrp + (size_t)pos * 16);
        dst4[0] = src4[0]; dst4[1] = src4[1]; dst4[2] = src4[2]; dst4[3] = src4[3];
    }
}

// ---------------- edge aggregation: one wave per dst node -------------------
// agg[d] = sum_e relu(A[col[e]] + B[d] + eattrp[e] @ Wm3)
__global__ __launch_bounds__(THREADS)
void edge_agg(const float* __restrict__ A, const float* __restrict__ Bb,
              const float* __restrict__ eattrp, const int* __restrict__ col,
              const int* __restrict__ rowptr, const float* __restrict__ Wm3,
              float* __restrict__ agg, int nN)
{
    __shared__ float W3s[16 * 128];
    const int t = threadIdx.x;

    // stage Wm3 (16x128 = 8 KB)
    *reinterpret_cast<float4*>(&W3s[t * 4])        = *reinterpret_cast<const float4*>(Wm3 + t * 4);
    *reinterpret_cast<float4*>(&W3s[1024 + t * 4]) = *reinterpret_cast<const float4*>(Wm3 + 1024 + t * 4);
    __syncthreads();

    const int lane = t & 63;
    const int wid  = __builtin_amdgcn_readfirstlane(t >> 6);
    const int d    = blockIdx.x * 4 + wid;
    if (d >= nN) return;

    // hoist this lane's Wm3 column pair into registers
    float2 w[16];
#pragma unroll
    for (int k = 0; k < 16; k++)
        w[k] = *reinterpret_cast<const float2*>(&W3s[k * 128 + lane * 2]);

    const float2 b2 = *reinterpret_cast<const float2*>(Bb + (size_t)d * 128 + lane * 2);
    float2 acc = make_float2(0.f, 0.f);

    const int beg = rowptr[d], end = rowptr[d + 1];
    for (int e = beg; e < end; e++) {
        const int s = col[e];
        const float2 a2 = *reinterpret_cast<const float2*>(A + (size_t)s * 128 + lane * 2);
        float vx = a2.x + b2.x;
        float vy = a2.y + b2.y;
        const float4* ea4 = reinterpret_cast<const float4*>(eattrp + (size_t)e * 16);
        const float4 e0 = ea4[0], e1 = ea4[1], e2 = ea4[2], e3 = ea4[3];
        const float ek[16] = {e0.x, e0.y, e0.z, e0.w, e1.x, e1.y, e1.z, e1.w,
                              e2.x, e2.y, e2.z, e2.w, e3.x, e3.y, e3.z, e3.w};
#pragma unroll
        for (int k = 0; k < 16; k++) {
            vx = fmaf(ek[k], w[k].x, vx);
            vy = fmaf(ek[k], w[k].y, vy);
        }
        acc.x += fmaxf(vx, 0.f);
        acc.y += fmaxf(vy, 0.f);
    }
    *reinterpret_cast<float2*>(agg + (size_t)d * 128 + lane * 2) = acc;
}

// Per-graph mean pool over sorted `batch`, then dot with W_pred.
__global__ __launch_bounds__(THREADS)
void pool_pred(const float* __restrict__ h, const int* __restrict__ batch,
               const float* __restrict__ Wp, const float* __restrict__ bp,
               float* __restrict__ out, int n)
{
    __shared__ float red[THREADS];
    const int g = blockIdx.x;
    const int t = threadIdx.x;

    int lo, hi;
    {
        int a = 0, b = n;
        while (a < b) { int m = (a + b) >> 1; if (batch[m] < g) a = m + 1; else b = m; }
        lo = a;
        b = n;
        while (a < b) { int m = (a + b) >> 1; if (batch[m] < g + 1) a = m + 1; else b = m; }
        hi = a;
    }
    const int cnt  = hi - lo;
    const int c    = t & 127;
    const int half = t >> 7;

    float s = 0.f;
    for (int i = lo + half; i < hi; i += 2) s += h[(size_t)i * 128 + c];
    red[t] = s;
    __syncthreads();

    if (t < 128) {
        float mean = (red[t] + red[t + 128]) / (float)max(cnt, 1);
        red[t] = mean * Wp[c];
    }
    __syncthreads();
    for (int off = 64; off > 0; off >>= 1) {
        if (t < off) red[t] += red[t + off];
        __syncthreads();
    }
    if (t == 0) out[g] = red[0] + bp[0];
}

extern "C" void kernel_launch(void* const* d_in, const int* in_sizes, int n_in,
                              void* d_out, int out_size, void* d_ws, size_t ws_size,
                              hipStream_t stream)
{
    const float* x      = (const float*)d_in[0];
    const int*   ei     = (const int*)  d_in[1];
    const float* eattr  = (const float*)d_in[2];
    const int*   batch  = (const int*)  d_in[3];
    const float* W_in   = (const float*)d_in[4];
    const float* b_in   = (const float*)d_in[5];
    const float* W_msg  = (const float*)d_in[6];
    const float* b_msg  = (const float*)d_in[7];
    const float* W_upd  = (const float*)d_in[8];
    const float* b_upd  = (const float*)d_in[9];
    const float* W_pred = (const float*)d_in[10];
    const float* b_pred = (const float*)d_in[11];
    float* out = (float*)d_out;

    const int nN = in_sizes[0] / 128;   // 50000
    const int nE = in_sizes[1] / 2;     // 800000
    const int* esrc = ei;
    const int* edst = ei + nE;

    // workspace carve-up
    float* h      = (float*)d_ws;
    float* A      = h      + (size_t)nN * 128;
    float* Bb     = A      + (size_t)nN * 128;
    float* agg    = Bb     + (size_t)nN * 128;
    float* eattrp = agg    + (size_t)nN * 128;
    int*   rowptr = (int*)(eattrp + (size_t)nE * 16);
    int*   wp     = rowptr + (nN + 1);
    int*   deg    = wp     + nN;
    int*   col    = deg    + nN;

    dim3 blk(THREADS);
    const int gx = (nN + 63) / 64;

    // ---- CSR build (graph constant across layers) ----
    zero_i32<<<64, blk, 0, stream>>>(deg, nN);
    csr_hist<<<256, blk, 0, stream>>>(edst, deg, nE);
    csr_scan<<<1, blk, 0, stream>>>(deg, rowptr, wp, nN);
    csr_scatter<<<256, blk, 0, stream>>>(esrc, edst, eattr, wp, col, eattrp, nE);

    // h = x @ W_in + b_in
    gemm_tile<false, false><<<gx, blk, 0, stream>>>(x, nullptr, W_in, b_in, nullptr, h, nN, 128);

    for (int l = 0; l < 4; l++) {
        const float* Wm = W_msg + (size_t)l * 272 * 128;
        const float* bm = b_msg + l * 128;
        const float* Wu = W_upd + (size_t)l * 256 * 128;
        const float* bu = b_upd + l * 128;

        // A = h @ Wm1 ; B = h @ Wm2 + b_msg
        gemm_tile<false, false><<<gx, blk, 0, stream>>>(h, nullptr, Wm,             nullptr, nullptr, A,  nN, 128);
        gemm_tile<false, false><<<gx, blk, 0, stream>>>(h, nullptr, Wm + 128 * 128, bm,      nullptr, Bb, nN, 128);

        // agg[d] = sum relu(A[src] + B[d] + e@Wm3)   (CSR, atomic-free)
        edge_agg<<<(nN + 3) / 4, blk, 0, stream>>>(A, Bb, eattrp, col, rowptr, Wm + 256 * 128, agg, nN);

        // h = h + relu([h, agg] @ W_upd + b_upd)   (in-place safe: blocks own rows)
        gemm_tile<true, true><<<gx, blk, 0, stream>>>(h, agg, Wu, bu, h, h, nN, 256);
    }

    pool_pred<<<64, blk, 0, stream>>>(h, batch, W_pred, b_pred, out, nN);
}

// Round 3
// 996.418 us; speedup vs baseline: 1.9238x; 1.2075x over previous
//
#include <hip/hip_runtime.h>

// ---------------------------------------------------------------------------
// GNN forward: h = x@W_in + b; 4x message-passing layers; mean-pool; predict.
// Decomposition: per-edge message relu([h_s,h_d,e]@Wm + b)
//   == relu(A[src] + B[dst] + e@Wm3), with A = h@Wm1, B = h@Wm2 + b.
// Graph is layer-invariant -> build CSR (by dst) once, aggregate atomic-free.
// CSR rowptr via 3-stage hierarchical scan (the single-block scan was 217us).
// ---------------------------------------------------------------------------

#define THREADS 256

// C[M x 128] = X[M x K] @ W[K x 128]  (+bias) (opt relu) (opt residual add)
// K = 128 (X1 only) or 256 (k<128 from X1, k>=128 from X2). Row stride 128.
template<bool RELU, bool RESID>
__global__ __launch_bounds__(THREADS)
void gemm_tile(const float* __restrict__ X1, const float* __restrict__ X2,
               const float* __restrict__ W, const float* __restrict__ bias,
               const float* __restrict__ resid, float* __restrict__ C,
               int M, int K)
{
    __shared__ float XsT[16][68];   // transposed X tile [k][m], padded
    __shared__ float Ws[16][128];   // W tile [k][n]

    const int t   = threadIdx.x;
    const int c0  = (t & 31) * 4;   // output cols c0..c0+3
    const int r0  = (t >> 5) * 8;   // output rows r0..r0+7 (within tile)
    const int mBase = blockIdx.x * 64;

    float acc[8][4];
#pragma unroll
    for (int i = 0; i < 8; i++)
#pragma unroll
        for (int j = 0; j < 4; j++) acc[i][j] = 0.f;

    const int sm = t >> 2;          // staging row 0..63
    const int sk = (t & 3) * 4;     // staging k quad
    const int gm = mBase + sm;
    const int wr0 = t >> 5;         // W staging row 0..7
    const int wc0 = (t & 31) * 4;

    for (int k0 = 0; k0 < K; k0 += 16) {
        const float* Xsrc = X1;
        int koff = k0;
        if (k0 >= 128) { Xsrc = X2; koff = k0 - 128; }

        float4 xv;
        if (gm < M) xv = *reinterpret_cast<const float4*>(Xsrc + (size_t)gm * 128 + koff + sk);
        else        xv = make_float4(0.f, 0.f, 0.f, 0.f);

        float4 wv0 = *reinterpret_cast<const float4*>(W + (size_t)(k0 + wr0) * 128 + wc0);
        float4 wv1 = *reinterpret_cast<const float4*>(W + (size_t)(k0 + wr0 + 8) * 128 + wc0);

        __syncthreads();  // previous iteration's consumers done

        XsT[sk + 0][sm] = xv.x;
        XsT[sk + 1][sm] = xv.y;
        XsT[sk + 2][sm] = xv.z;
        XsT[sk + 3][sm] = xv.w;
        *reinterpret_cast<float4*>(&Ws[wr0][wc0])     = wv0;
        *reinterpret_cast<float4*>(&Ws[wr0 + 8][wc0]) = wv1;

        __syncthreads();

#pragma unroll
        for (int kk = 0; kk < 16; kk++) {
            float4 wv = *reinterpret_cast<const float4*>(&Ws[kk][c0]);
            float4 xa = *reinterpret_cast<const float4*>(&XsT[kk][r0]);
            float4 xb = *reinterpret_cast<const float4*>(&XsT[kk][r0 + 4]);
            float xr[8] = {xa.x, xa.y, xa.z, xa.w, xb.x, xb.y, xb.z, xb.w};
#pragma unroll
            for (int i = 0; i < 8; i++) {
                acc[i][0] = fmaf(xr[i], wv.x, acc[i][0]);
                acc[i][1] = fmaf(xr[i], wv.y, acc[i][1]);
                acc[i][2] = fmaf(xr[i], wv.z, acc[i][2]);
                acc[i][3] = fmaf(xr[i], wv.w, acc[i][3]);
            }
        }
    }

#pragma unroll
    for (int i = 0; i < 8; i++) {
        int gr = mBase + r0 + i;
        if (gr >= M) continue;
        float4 v;
        v.x = acc[i][0]; v.y = acc[i][1]; v.z = acc[i][2]; v.w = acc[i][3];
        if (bias) {
            v.x += bias[c0 + 0]; v.y += bias[c0 + 1];
            v.z += bias[c0 + 2]; v.w += bias[c0 + 3];
        }
        if (RELU) {
            v.x = fmaxf(v.x, 0.f); v.y = fmaxf(v.y, 0.f);
            v.z = fmaxf(v.z, 0.f); v.w = fmaxf(v.w, 0.f);
        }
        if (RESID) {
            float4 rv = *reinterpret_cast<const float4*>(resid + (size_t)gr * 128 + c0);
            v.x += rv.x; v.y += rv.y; v.z += rv.z; v.w += rv.w;
        }
        *reinterpret_cast<float4*>(C + (size_t)gr * 128 + c0) = v;
    }
}

__global__ __launch_bounds__(THREADS)
void zero_i32(int* __restrict__ p, int n)
{
    int i = blockIdx.x * blockDim.x + threadIdx.x;
    int stride = gridDim.x * blockDim.x;
    for (; i < n; i += stride) p[i] = 0;
}

// ---------------- CSR build (once per call; graph is layer-invariant) -------

__global__ __launch_bounds__(THREADS)
void csr_hist(const int* __restrict__ edst, int* __restrict__ deg, int nE)
{
    int i = blockIdx.x * blockDim.x + threadIdx.x;
    int stride = gridDim.x * blockDim.x;
    for (; i < nE; i += stride) atomicAdd(&deg[edst[i]], 1);
}

// stage 1: per-block (1024-element chunk) inclusive scan; chunk totals -> psum
__global__ __launch_bounds__(THREADS)
void scan_stage1(const int* __restrict__ deg, int* __restrict__ incl,
                 int* __restrict__ psum, int n)
{
    __shared__ int buf[THREADS];
    const int t = threadIdx.x;
    const int base = blockIdx.x * 1024 + t * 4;

    int v0 = (base + 0 < n) ? deg[base + 0] : 0;
    int v1 = (base + 1 < n) ? deg[base + 1] : 0;
    int v2 = (base + 2 < n) ? deg[base + 2] : 0;
    int v3 = (base + 3 < n) ? deg[base + 3] : 0;
    const int s = v0 + v1 + v2 + v3;

    buf[t] = s;
    __syncthreads();
#pragma unroll
    for (int off = 1; off < THREADS; off <<= 1) {
        int x = (t >= off) ? buf[t - off] : 0;
        __syncthreads();
        buf[t] += x;
        __syncthreads();
    }
    const int excl = buf[t] - s;

    if (base + 0 < n) incl[base + 0] = excl + v0;
    if (base + 1 < n) incl[base + 1] = excl + v0 + v1;
    if (base + 2 < n) incl[base + 2] = excl + v0 + v1 + v2;
    if (base + 3 < n) incl[base + 3] = excl + s;
    if (t == THREADS - 1) psum[blockIdx.x] = buf[THREADS - 1];
}

// stage 2: single-block exclusive scan of chunk totals (nb <= 256)
__global__ __launch_bounds__(THREADS)
void scan_stage2(int* __restrict__ psum, int nb)
{
    __shared__ int buf[THREADS];
    const int t = threadIdx.x;
    int v = (t < nb) ? psum[t] : 0;
    buf[t] = v;
    __syncthreads();
#pragma unroll
    for (int off = 1; off < THREADS; off <<= 1) {
        int x = (t >= off) ? buf[t - off] : 0;
        __syncthreads();
        buf[t] += x;
        __syncthreads();
    }
    if (t < nb) psum[t] = buf[t] - v;   // exclusive
}

// stage 3: rowptr[i] = wp[i] = exclusive prefix; rowptr[n] = nE (analytic)
__global__ __launch_bounds__(THREADS)
void scan_stage3(const int* __restrict__ incl, const int* __restrict__ deg,
                 const int* __restrict__ psum, int* __restrict__ rowptr,
                 int* __restrict__ wp, int n, int nE)
{
    int i = blockIdx.x * blockDim.x + threadIdx.x;
    int stride = gridDim.x * blockDim.x;
    for (; i < n; i += stride) {
        int ex = incl[i] - deg[i] + psum[i >> 10];
        rowptr[i] = ex;
        wp[i]     = ex;
    }
    if (blockIdx.x == 0 && threadIdx.x == 0) rowptr[n] = nE;
}

// scatter edges into CSR order; permute edge_attr rows alongside
__global__ __launch_bounds__(THREADS)
void csr_scatter(const int* __restrict__ esrc, const int* __restrict__ edst,
                 const float* __restrict__ eattr, int* __restrict__ wp,
                 int* __restrict__ col, float* __restrict__ eattrp, int nE)
{
    int i = blockIdx.x * blockDim.x + threadIdx.x;
    int stride = gridDim.x * blockDim.x;
    for (; i < nE; i += stride) {
        int d = edst[i];
        int pos = atomicAdd(&wp[d], 1);
        col[pos] = esrc[i];
        const float4* src4 = reinterpret_cast<const float4*>(eattr + (size_t)i * 16);
        float4*       dst4 = reinterpret_cast<float4*>(eattrp + (size_t)pos * 16);
        dst4[0] = src4[0]; dst4[1] = src4[1]; dst4[2] = src4[2]; dst4[3] = src4[3];
    }
}

// ---------------- edge aggregation: one wave per dst node -------------------
// agg[d] = sum_e relu(A[col[e]] + B[d] + eattrp[e] @ Wm3)
__global__ __launch_bounds__(THREADS)
void edge_agg(const float* __restrict__ A, const float* __restrict__ Bb,
              const float* __restrict__ eattrp, const int* __restrict__ col,
              const int* __restrict__ rowptr, const float* __restrict__ Wm3,
              float* __restrict__ agg, int nN)
{
    __shared__ float W3s[16 * 128];
    const int t = threadIdx.x;

    // stage Wm3 (16x128 = 8 KB)
    *reinterpret_cast<float4*>(&W3s[t * 4])        = *reinterpret_cast<const float4*>(Wm3 + t * 4);
    *reinterpret_cast<float4*>(&W3s[1024 + t * 4]) = *reinterpret_cast<const float4*>(Wm3 + 1024 + t * 4);
    __syncthreads();

    const int lane = t & 63;
    const int wid  = __builtin_amdgcn_readfirstlane(t >> 6);
    const int d    = blockIdx.x * 4 + wid;
    if (d >= nN) return;

    // hoist this lane's Wm3 column pair into registers
    float2 w[16];
#pragma unroll
    for (int k = 0; k < 16; k++)
        w[k] = *reinterpret_cast<const float2*>(&W3s[k * 128 + lane * 2]);

    const float2 b2 = *reinterpret_cast<const float2*>(Bb + (size_t)d * 128 + lane * 2);
    float2 acc = make_float2(0.f, 0.f);

    const int beg = rowptr[d], end = rowptr[d + 1];
    for (int e = beg; e < end; e++) {
        const int s = col[e];
        const float2 a2 = *reinterpret_cast<const float2*>(A + (size_t)s * 128 + lane * 2);
        float vx = a2.x + b2.x;
        float vy = a2.y + b2.y;
        const float4* ea4 = reinterpret_cast<const float4*>(eattrp + (size_t)e * 16);
        const float4 e0 = ea4[0], e1 = ea4[1], e2 = ea4[2], e3 = ea4[3];
        const float ek[16] = {e0.x, e0.y, e0.z, e0.w, e1.x, e1.y, e1.z, e1.w,
                              e2.x, e2.y, e2.z, e2.w, e3.x, e3.y, e3.z, e3.w};
#pragma unroll
        for (int k = 0; k < 16; k++) {
            vx = fmaf(ek[k], w[k].x, vx);
            vy = fmaf(ek[k], w[k].y, vy);
        }
        acc.x += fmaxf(vx, 0.f);
        acc.y += fmaxf(vy, 0.f);
    }
    *reinterpret_cast<float2*>(agg + (size_t)d * 128 + lane * 2) = acc;
}

// Per-graph mean pool over sorted `batch`, then dot with W_pred.
__global__ __launch_bounds__(THREADS)
void pool_pred(const float* __restrict__ h, const int* __restrict__ batch,
               const float* __restrict__ Wp, const float* __restrict__ bp,
               float* __restrict__ out, int n)
{
    __shared__ float red[THREADS];
    const int g = blockIdx.x;
    const int t = threadIdx.x;

    int lo, hi;
    {
        int a = 0, b = n;
        while (a < b) { int m = (a + b) >> 1; if (batch[m] < g) a = m + 1; else b = m; }
        lo = a;
        b = n;
        while (a < b) { int m = (a + b) >> 1; if (batch[m] < g + 1) a = m + 1; else b = m; }
        hi = a;
    }
    const int cnt  = hi - lo;
    const int c    = t & 127;
    const int half = t >> 7;

    float s = 0.f;
    for (int i = lo + half; i < hi; i += 2) s += h[(size_t)i * 128 + c];
    red[t] = s;
    __syncthreads();

    if (t < 128) {
        float mean = (red[t] + red[t + 128]) / (float)max(cnt, 1);
        red[t] = mean * Wp[c];
    }
    __syncthreads();
    for (int off = 64; off > 0; off >>= 1) {
        if (t < off) red[t] += red[t + off];
        __syncthreads();
    }
    if (t == 0) out[g] = red[0] + bp[0];
}

extern "C" void kernel_launch(void* const* d_in, const int* in_sizes, int n_in,
                              void* d_out, int out_size, void* d_ws, size_t ws_size,
                              hipStream_t stream)
{
    const float* x      = (const float*)d_in[0];
    const int*   ei     = (const int*)  d_in[1];
    const float* eattr  = (const float*)d_in[2];
    const int*   batch  = (const int*)  d_in[3];
    const float* W_in   = (const float*)d_in[4];
    const float* b_in   = (const float*)d_in[5];
    const float* W_msg  = (const float*)d_in[6];
    const float* b_msg  = (const float*)d_in[7];
    const float* W_upd  = (const float*)d_in[8];
    const float* b_upd  = (const float*)d_in[9];
    const float* W_pred = (const float*)d_in[10];
    const float* b_pred = (const float*)d_in[11];
    float* out = (float*)d_out;

    const int nN = in_sizes[0] / 128;   // 50000
    const int nE = in_sizes[1] / 2;     // 800000
    const int* esrc = ei;
    const int* edst = ei + nE;

    // workspace carve-up
    float* h      = (float*)d_ws;
    float* A      = h      + (size_t)nN * 128;
    float* Bb     = A      + (size_t)nN * 128;
    float* agg    = Bb     + (size_t)nN * 128;
    float* eattrp = agg    + (size_t)nN * 128;
    int*   rowptr = (int*)(eattrp + (size_t)nE * 16);
    int*   wp     = rowptr + (nN + 1);
    int*   deg    = wp     + nN;
    int*   incl   = deg    + nN;
    int*   psum   = incl   + nN;
    int*   col    = psum   + 256;

    dim3 blk(THREADS);
    const int gx = (nN + 63) / 64;
    const int nChunks = (nN + 1023) / 1024;   // 49

    // ---- CSR build (graph constant across layers) ----
    zero_i32<<<64, blk, 0, stream>>>(deg, nN);
    csr_hist<<<256, blk, 0, stream>>>(edst, deg, nE);
    scan_stage1<<<nChunks, blk, 0, stream>>>(deg, incl, psum, nN);
    scan_stage2<<<1, blk, 0, stream>>>(psum, nChunks);
    scan_stage3<<<64, blk, 0, stream>>>(incl, deg, psum, rowptr, wp, nN, nE);
    csr_scatter<<<256, blk, 0, stream>>>(esrc, edst, eattr, wp, col, eattrp, nE);

    // h = x @ W_in + b_in
    gemm_tile<false, false><<<gx, blk, 0, stream>>>(x, nullptr, W_in, b_in, nullptr, h, nN, 128);

    for (int l = 0; l < 4; l++) {
        const float* Wm = W_msg + (size_t)l * 272 * 128;
        const float* bm = b_msg + l * 128;
        const float* Wu = W_upd + (size_t)l * 256 * 128;
        const float* bu = b_upd + l * 128;

        // A = h @ Wm1 ; B = h @ Wm2 + b_msg
        gemm_tile<false, false><<<gx, blk, 0, stream>>>(h, nullptr, Wm,             nullptr, nullptr, A,  nN, 128);
        gemm_tile<false, false><<<gx, blk, 0, stream>>>(h, nullptr, Wm + 128 * 128, bm,      nullptr, Bb, nN, 128);

        // agg[d] = sum relu(A[src] + B[d] + e@Wm3)   (CSR, atomic-free)
        edge_agg<<<(nN + 3) / 4, blk, 0, stream>>>(A, Bb, eattrp, col, rowptr, Wm + 256 * 128, agg, nN);

        // h = h + relu([h, agg] @ W_upd + b_upd)   (in-place safe: blocks own rows)
        gemm_tile<true, true><<<gx, blk, 0, stream>>>(h, agg, Wu, bu, h, h, nN, 256);
    }

    pool_pred<<<64, blk, 0, stream>>>(h, batch, W_pred, b_pred, out, nN);
}

// Round 4
// 945.176 us; speedup vs baseline: 2.0280x; 1.0542x over previous
//
#include <hip/hip_runtime.h>

// ---------------------------------------------------------------------------
// GNN forward: h = x@W_in + b; 4x message-passing layers; mean-pool; predict.
// Decomposition: per-edge message relu([h_s,h_d,e]@Wm + b)
//   == relu(A[src] + B[dst] + e@Wm3), with A = h@Wm1, B = h@Wm2 + b.
// Graph is layer-invariant -> build CSR (by dst) once, aggregate atomic-free.
// CSR rowptr via 3-stage hierarchical scan. Pool via 2-stage partial sums
// (single-stage 64-block pool was latency-bound at 106us).
// ---------------------------------------------------------------------------

#define THREADS 256

// C[M x 128] = X[M x K] @ W[K x 128]  (+bias) (opt relu) (opt residual add)
// K = 128 (X1 only) or 256 (k<128 from X1, k>=128 from X2). Row stride 128.
template<bool RELU, bool RESID>
__global__ __launch_bounds__(THREADS)
void gemm_tile(const float* __restrict__ X1, const float* __restrict__ X2,
               const float* __restrict__ W, const float* __restrict__ bias,
               const float* __restrict__ resid, float* __restrict__ C,
               int M, int K)
{
    __shared__ float XsT[16][68];   // transposed X tile [k][m], padded
    __shared__ float Ws[16][128];   // W tile [k][n]

    const int t   = threadIdx.x;
    const int c0  = (t & 31) * 4;   // output cols c0..c0+3
    const int r0  = (t >> 5) * 8;   // output rows r0..r0+7 (within tile)
    const int mBase = blockIdx.x * 64;

    float acc[8][4];
#pragma unroll
    for (int i = 0; i < 8; i++)
#pragma unroll
        for (int j = 0; j < 4; j++) acc[i][j] = 0.f;

    const int sm = t >> 2;          // staging row 0..63
    const int sk = (t & 3) * 4;     // staging k quad
    const int gm = mBase + sm;
    const int wr0 = t >> 5;         // W staging row 0..7
    const int wc0 = (t & 31) * 4;

    for (int k0 = 0; k0 < K; k0 += 16) {
        const float* Xsrc = X1;
        int koff = k0;
        if (k0 >= 128) { Xsrc = X2; koff = k0 - 128; }

        float4 xv;
        if (gm < M) xv = *reinterpret_cast<const float4*>(Xsrc + (size_t)gm * 128 + koff + sk);
        else        xv = make_float4(0.f, 0.f, 0.f, 0.f);

        float4 wv0 = *reinterpret_cast<const float4*>(W + (size_t)(k0 + wr0) * 128 + wc0);
        float4 wv1 = *reinterpret_cast<const float4*>(W + (size_t)(k0 + wr0 + 8) * 128 + wc0);

        __syncthreads();  // previous iteration's consumers done

        XsT[sk + 0][sm] = xv.x;
        XsT[sk + 1][sm] = xv.y;
        XsT[sk + 2][sm] = xv.z;
        XsT[sk + 3][sm] = xv.w;
        *reinterpret_cast<float4*>(&Ws[wr0][wc0])     = wv0;
        *reinterpret_cast<float4*>(&Ws[wr0 + 8][wc0]) = wv1;

        __syncthreads();

#pragma unroll
        for (int kk = 0; kk < 16; kk++) {
            float4 wv = *reinterpret_cast<const float4*>(&Ws[kk][c0]);
            float4 xa = *reinterpret_cast<const float4*>(&XsT[kk][r0]);
            float4 xb = *reinterpret_cast<const float4*>(&XsT[kk][r0 + 4]);
            float xr[8] = {xa.x, xa.y, xa.z, xa.w, xb.x, xb.y, xb.z, xb.w};
#pragma unroll
            for (int i = 0; i < 8; i++) {
                acc[i][0] = fmaf(xr[i], wv.x, acc[i][0]);
                acc[i][1] = fmaf(xr[i], wv.y, acc[i][1]);
                acc[i][2] = fmaf(xr[i], wv.z, acc[i][2]);
                acc[i][3] = fmaf(xr[i], wv.w, acc[i][3]);
            }
        }
    }

#pragma unroll
    for (int i = 0; i < 8; i++) {
        int gr = mBase + r0 + i;
        if (gr >= M) continue;
        float4 v;
        v.x = acc[i][0]; v.y = acc[i][1]; v.z = acc[i][2]; v.w = acc[i][3];
        if (bias) {
            v.x += bias[c0 + 0]; v.y += bias[c0 + 1];
            v.z += bias[c0 + 2]; v.w += bias[c0 + 3];
        }
        if (RELU) {
            v.x = fmaxf(v.x, 0.f); v.y = fmaxf(v.y, 0.f);
            v.z = fmaxf(v.z, 0.f); v.w = fmaxf(v.w, 0.f);
        }
        if (RESID) {
            float4 rv = *reinterpret_cast<const float4*>(resid + (size_t)gr * 128 + c0);
            v.x += rv.x; v.y += rv.y; v.z += rv.z; v.w += rv.w;
        }
        *reinterpret_cast<float4*>(C + (size_t)gr * 128 + c0) = v;
    }
}

__global__ __launch_bounds__(THREADS)
void zero_i32(int* __restrict__ p, int n)
{
    int i = blockIdx.x * blockDim.x + threadIdx.x;
    int stride = gridDim.x * blockDim.x;
    for (; i < n; i += stride) p[i] = 0;
}

// ---------------- CSR build (once per call; graph is layer-invariant) -------

__global__ __launch_bounds__(THREADS)
void csr_hist(const int* __restrict__ edst, int* __restrict__ deg, int nE)
{
    int i = blockIdx.x * blockDim.x + threadIdx.x;
    int stride = gridDim.x * blockDim.x;
    for (; i < nE; i += stride) atomicAdd(&deg[edst[i]], 1);
}

// stage 1: per-block (1024-element chunk) inclusive scan; chunk totals -> psum
__global__ __launch_bounds__(THREADS)
void scan_stage1(const int* __restrict__ deg, int* __restrict__ incl,
                 int* __restrict__ psum, int n)
{
    __shared__ int buf[THREADS];
    const int t = threadIdx.x;
    const int base = blockIdx.x * 1024 + t * 4;

    int v0 = (base + 0 < n) ? deg[base + 0] : 0;
    int v1 = (base + 1 < n) ? deg[base + 1] : 0;
    int v2 = (base + 2 < n) ? deg[base + 2] : 0;
    int v3 = (base + 3 < n) ? deg[base + 3] : 0;
    const int s = v0 + v1 + v2 + v3;

    buf[t] = s;
    __syncthreads();
#pragma unroll
    for (int off = 1; off < THREADS; off <<= 1) {
        int x = (t >= off) ? buf[t - off] : 0;
        __syncthreads();
        buf[t] += x;
        __syncthreads();
    }
    const int excl = buf[t] - s;

    if (base + 0 < n) incl[base + 0] = excl + v0;
    if (base + 1 < n) incl[base + 1] = excl + v0 + v1;
    if (base + 2 < n) incl[base + 2] = excl + v0 + v1 + v2;
    if (base + 3 < n) incl[base + 3] = excl + s;
    if (t == THREADS - 1) psum[blockIdx.x] = buf[THREADS - 1];
}

// stage 2: single-block exclusive scan of chunk totals (nb <= 256)
__global__ __launch_bounds__(THREADS)
void scan_stage2(int* __restrict__ psum, int nb)
{
    __shared__ int buf[THREADS];
    const int t = threadIdx.x;
    int v = (t < nb) ? psum[t] : 0;
    buf[t] = v;
    __syncthreads();
#pragma unroll
    for (int off = 1; off < THREADS; off <<= 1) {
        int x = (t >= off) ? buf[t - off] : 0;
        __syncthreads();
        buf[t] += x;
        __syncthreads();
    }
    if (t < nb) psum[t] = buf[t] - v;   // exclusive
}

// stage 3: rowptr[i] = wp[i] = exclusive prefix; rowptr[n] = nE (analytic)
__global__ __launch_bounds__(THREADS)
void scan_stage3(const int* __restrict__ incl, const int* __restrict__ deg,
                 const int* __restrict__ psum, int* __restrict__ rowptr,
                 int* __restrict__ wp, int n, int nE)
{
    int i = blockIdx.x * blockDim.x + threadIdx.x;
    int stride = gridDim.x * blockDim.x;
    for (; i < n; i += stride) {
        int ex = incl[i] - deg[i] + psum[i >> 10];
        rowptr[i] = ex;
        wp[i]     = ex;
    }
    if (blockIdx.x == 0 && threadIdx.x == 0) rowptr[n] = nE;
}

// scatter edges into CSR order; permute edge_attr rows alongside
__global__ __launch_bounds__(THREADS)
void csr_scatter(const int* __restrict__ esrc, const int* __restrict__ edst,
                 const float* __restrict__ eattr, int* __restrict__ wp,
                 int* __restrict__ col, float* __restrict__ eattrp, int nE)
{
    int i = blockIdx.x * blockDim.x + threadIdx.x;
    int stride = gridDim.x * blockDim.x;
    for (; i < nE; i += stride) {
        int d = edst[i];
        int pos = atomicAdd(&wp[d], 1);
        col[pos] = esrc[i];
        const float4* src4 = reinterpret_cast<const float4*>(eattr + (size_t)i * 16);
        float4*       dst4 = reinterpret_cast<float4*>(eattrp + (size_t)pos * 16);
        dst4[0] = src4[0]; dst4[1] = src4[1]; dst4[2] = src4[2]; dst4[3] = src4[3];
    }
}

// ---------------- edge aggregation: one wave per dst node -------------------
// agg[d] = sum_e relu(A[col[e]] + B[d] + eattrp[e] @ Wm3)
__global__ __launch_bounds__(THREADS)
void edge_agg(const float* __restrict__ A, const float* __restrict__ Bb,
              const float* __restrict__ eattrp, const int* __restrict__ col,
              const int* __restrict__ rowptr, const float* __restrict__ Wm3,
              float* __restrict__ agg, int nN)
{
    __shared__ float W3s[16 * 128];
    const int t = threadIdx.x;

    // stage Wm3 (16x128 = 8 KB)
    *reinterpret_cast<float4*>(&W3s[t * 4])        = *reinterpret_cast<const float4*>(Wm3 + t * 4);
    *reinterpret_cast<float4*>(&W3s[1024 + t * 4]) = *reinterpret_cast<const float4*>(Wm3 + 1024 + t * 4);
    __syncthreads();

    const int lane = t & 63;
    const int wid  = __builtin_amdgcn_readfirstlane(t >> 6);
    const int d    = blockIdx.x * 4 + wid;
    if (d >= nN) return;

    // hoist this lane's Wm3 column pair into registers
    float2 w[16];
#pragma unroll
    for (int k = 0; k < 16; k++)
        w[k] = *reinterpret_cast<const float2*>(&W3s[k * 128 + lane * 2]);

    const float2 b2 = *reinterpret_cast<const float2*>(Bb + (size_t)d * 128 + lane * 2);
    float2 acc = make_float2(0.f, 0.f);

    const int beg = rowptr[d], end = rowptr[d + 1];
    for (int e = beg; e < end; e++) {
        const int s = col[e];
        const float2 a2 = *reinterpret_cast<const float2*>(A + (size_t)s * 128 + lane * 2);
        float vx = a2.x + b2.x;
        float vy = a2.y + b2.y;
        const float4* ea4 = reinterpret_cast<const float4*>(eattrp + (size_t)e * 16);
        const float4 e0 = ea4[0], e1 = ea4[1], e2 = ea4[2], e3 = ea4[3];
        const float ek[16] = {e0.x, e0.y, e0.z, e0.w, e1.x, e1.y, e1.z, e1.w,
                              e2.x, e2.y, e2.z, e2.w, e3.x, e3.y, e3.z, e3.w};
#pragma unroll
        for (int k = 0; k < 16; k++) {
            vx = fmaf(ek[k], w[k].x, vx);
            vy = fmaf(ek[k], w[k].y, vy);
        }
        acc.x += fmaxf(vx, 0.f);
        acc.y += fmaxf(vy, 0.f);
    }
    *reinterpret_cast<float2*>(agg + (size_t)d * 128 + lane * 2) = acc;
}

// ---------------- pooling: 2-stage (partial sums -> predict) ----------------

// stage 1: contiguous 256-row chunks; run-length local accumulate (batch is
// sorted), flush one atomicAdd per (graph-run, channel).
__global__ __launch_bounds__(THREADS)
void pool_partial(const float* __restrict__ h, const int* __restrict__ batch,
                  float* __restrict__ hgsum, int n)
{
    const int t    = threadIdx.x;
    const int c    = t & 127;
    const int half = t >> 7;
    const int beg  = blockIdx.x * 256;
    const int end  = min(beg + 256, n);
    if (beg >= n) return;

    int   cur = -1;
    float acc = 0.f;
    for (int r = beg + half; r < end; r += 2) {
        int g = batch[r];
        if (g != cur) {
            if (cur >= 0) atomicAdd(&hgsum[(size_t)cur * 128 + c], acc);
            cur = g; acc = 0.f;
        }
        acc += h[(size_t)r * 128 + c];
    }
    if (cur >= 0) atomicAdd(&hgsum[(size_t)cur * 128 + c], acc);
}

// stage 2: per-graph mean + dot(W_pred) + bias
__global__ __launch_bounds__(THREADS)
void pool_final(const float* __restrict__ hgsum, const int* __restrict__ batch,
                const float* __restrict__ Wp, const float* __restrict__ bp,
                float* __restrict__ out, int n)
{
    __shared__ float red[128];
    const int g = blockIdx.x;
    const int t = threadIdx.x;
    if (t >= 128) return;

    int lo, hi;
    {
        int a = 0, b = n;
        while (a < b) { int m = (a + b) >> 1; if (batch[m] < g) a = m + 1; else b = m; }
        lo = a;
        b = n;
        while (a < b) { int m = (a + b) >> 1; if (batch[m] < g + 1) a = m + 1; else b = m; }
        hi = a;
    }
    const int cnt = hi - lo;

    float v = hgsum[(size_t)g * 128 + t] / (float)max(cnt, 1);
    red[t] = v * Wp[t];
    __syncthreads();
    for (int off = 64; off > 0; off >>= 1) {
        if (t < off) red[t] += red[t + off];
        __syncthreads();
    }
    if (t == 0) out[g] = red[0] + bp[0];
}

extern "C" void kernel_launch(void* const* d_in, const int* in_sizes, int n_in,
                              void* d_out, int out_size, void* d_ws, size_t ws_size,
                              hipStream_t stream)
{
    const float* x      = (const float*)d_in[0];
    const int*   ei     = (const int*)  d_in[1];
    const float* eattr  = (const float*)d_in[2];
    const int*   batch  = (const int*)  d_in[3];
    const float* W_in   = (const float*)d_in[4];
    const float* b_in   = (const float*)d_in[5];
    const float* W_msg  = (const float*)d_in[6];
    const float* b_msg  = (const float*)d_in[7];
    const float* W_upd  = (const float*)d_in[8];
    const float* b_upd  = (const float*)d_in[9];
    const float* W_pred = (const float*)d_in[10];
    const float* b_pred = (const float*)d_in[11];
    float* out = (float*)d_out;

    const int nN = in_sizes[0] / 128;   // 50000
    const int nE = in_sizes[1] / 2;     // 800000
    const int* esrc = ei;
    const int* edst = ei + nE;

    // workspace carve-up
    float* h      = (float*)d_ws;
    float* A      = h      + (size_t)nN * 128;
    float* Bb     = A      + (size_t)nN * 128;
    float* agg    = Bb     + (size_t)nN * 128;
    float* eattrp = agg    + (size_t)nN * 128;
    float* hgsum  = eattrp + (size_t)nE * 16;
    int*   rowptr = (int*)(hgsum + 64 * 128);
    int*   wp     = rowptr + (nN + 1);
    int*   deg    = wp     + nN;
    int*   incl   = deg    + nN;
    int*   psum   = incl   + nN;
    int*   col    = psum   + 256;

    dim3 blk(THREADS);
    const int gx = (nN + 63) / 64;
    const int nChunks = (nN + 1023) / 1024;   // 49

    // ---- CSR build (graph constant across layers) ----
    zero_i32<<<64, blk, 0, stream>>>(deg, nN);
    csr_hist<<<256, blk, 0, stream>>>(edst, deg, nE);
    scan_stage1<<<nChunks, blk, 0, stream>>>(deg, incl, psum, nN);
    scan_stage2<<<1, blk, 0, stream>>>(psum, nChunks);
    scan_stage3<<<64, blk, 0, stream>>>(incl, deg, psum, rowptr, wp, nN, nE);
    csr_scatter<<<256, blk, 0, stream>>>(esrc, edst, eattr, wp, col, eattrp, nE);

    // h = x @ W_in + b_in
    gemm_tile<false, false><<<gx, blk, 0, stream>>>(x, nullptr, W_in, b_in, nullptr, h, nN, 128);

    for (int l = 0; l < 4; l++) {
        const float* Wm = W_msg + (size_t)l * 272 * 128;
        const float* bm = b_msg + l * 128;
        const float* Wu = W_upd + (size_t)l * 256 * 128;
        const float* bu = b_upd + l * 128;

        // A = h @ Wm1 ; B = h @ Wm2 + b_msg
        gemm_tile<false, false><<<gx, blk, 0, stream>>>(h, nullptr, Wm,             nullptr, nullptr, A,  nN, 128);
        gemm_tile<false, false><<<gx, blk, 0, stream>>>(h, nullptr, Wm + 128 * 128, bm,      nullptr, Bb, nN, 128);

        // agg[d] = sum relu(A[src] + B[d] + e@Wm3)   (CSR, atomic-free)
        edge_agg<<<(nN + 3) / 4, blk, 0, stream>>>(A, Bb, eattrp, col, rowptr, Wm + 256 * 128, agg, nN);

        // h = h + relu([h, agg] @ W_upd + b_upd)   (in-place safe: blocks own rows)
        gemm_tile<true, true><<<gx, blk, 0, stream>>>(h, agg, Wu, bu, h, h, nN, 256);
    }

    // ---- 2-stage mean pool + predict ----
    zero_i32<<<16, blk, 0, stream>>>((int*)hgsum, 64 * 128);
    pool_partial<<<(nN + 255) / 256, blk, 0, stream>>>(h, batch, hgsum, nN);
    pool_final<<<64, blk, 0, stream>>>(hgsum, batch, W_pred, b_pred, out, nN);
}

// Round 5
// 666.081 us; speedup vs baseline: 2.8778x; 1.4190x over previous
//
#include <hip/hip_runtime.h>

// ---------------------------------------------------------------------------
// GNN forward: h = x@W_in + b; 4x message-passing layers; mean-pool; predict.
// Decomposition: per-edge message relu([h_s,h_d,e]@Wm + b)
//   == relu(A[src] + B[dst] + e@Wm3), with A = h@Wm1, B = h@Wm2 + b.
// Graph is layer-invariant -> CSR (by dst) once, atomic-free aggregation.
// GEMMs: bf16 MFMA (16x16x32), weights pre-transposed to [n][k] bf16 once.
// All inter-kernel buffers stay fp32.
// ---------------------------------------------------------------------------

#define THREADS 256

typedef __attribute__((ext_vector_type(8))) short short8v;
typedef __attribute__((ext_vector_type(4))) float f32x4;

__device__ inline unsigned short f2bf(float f)   // RNE float->bf16
{
    unsigned int u = __float_as_uint(f);
    return (unsigned short)((u + 0x7FFFu + ((u >> 16) & 1u)) >> 16);
}

// ---- one-shot weight convert+transpose: W[k][128] f32 -> Wt[n][K] bf16 ----
// jobs: 0:W_in(K=128) 1-4:Wm1[l] 5-8:Wm2[l] (K=128) 9-12:W_upd[l] (K=256)
__global__ __launch_bounds__(THREADS)
void wconv_all(const float* __restrict__ W_in, const float* __restrict__ W_msg,
               const float* __restrict__ W_upd, unsigned short* __restrict__ wbf)
{
    int b = blockIdx.x;
    int job, kb;
    if (b < 576) { job = b >> 6; kb = b & 63; }
    else         { int r = b - 576; job = 9 + (r >> 7); kb = r & 127; }

    const float* src;
    unsigned short* dst;
    int K;
    if (job == 0)      { src = W_in;                                  dst = wbf;                       K = 128; }
    else if (job <= 4) { int l = job - 1; src = W_msg + (size_t)l * 272 * 128;             dst = wbf + 16384  + l * 16384; K = 128; }
    else if (job <= 8) { int l = job - 5; src = W_msg + (size_t)l * 272 * 128 + 128 * 128; dst = wbf + 81920  + l * 16384; K = 128; }
    else               { int l = job - 9; src = W_upd + (size_t)l * 256 * 128;             dst = wbf + 147456 + l * 32768; K = 256; }

    int i = kb * 256 + threadIdx.x;      // i < K*128
    int k = i >> 7, n = i & 127;
    dst[n * K + k] = f2bf(src[i]);
}

// ---- bf16 MFMA GEMM: C[M x 128] = X[M x K] @ W[K x 128] (+bias/relu/resid)
// X fp32 (rows from X1 for k<128, X2 for k>=128); Wt bf16 [128 n][K k].
// Block: 64 M x 128 N, 4 waves (wave w -> rows w*16..+16, all cols).
template<bool RELU, bool RESID>
__global__ __launch_bounds__(THREADS)
void gemm_bf16(const float* __restrict__ X1, const float* __restrict__ X2,
               const unsigned short* __restrict__ Wt, const float* __restrict__ bias,
               const float* __restrict__ resid, float* __restrict__ C,
               int M, int K)
{
    __shared__ unsigned short Als[64 * 40];    // [m][k] stride 40 (<=2-way bank)
    __shared__ unsigned short Bls[128 * 40];   // [n][k] stride 40

    const int t = threadIdx.x;
    const int w = t >> 6;
    const int l = t & 63;
    const int r  = l & 15;       // fragment row (A) / col (B)
    const int kb = l >> 4;       // k-chunk 0..3 (8 elems each)
    const int mBase = blockIdx.x * 64;

    f32x4 acc[8];
#pragma unroll
    for (int c = 0; c < 8; c++) acc[c] = (f32x4){0.f, 0.f, 0.f, 0.f};

    // staging coords
    const int am = t >> 2;               // A row 0..63
    const int ak = (t & 3) * 8;          // A k-octet
    const int agr = min(mBase + am, M - 1);

    for (int k0 = 0; k0 < K; k0 += 32) {
        const float* Xs = X1;
        int ko = k0;
        if (k0 >= 128) { Xs = X2; ko = k0 - 128; }

        // A: read 8 floats, convert to 8 bf16
        float4 f0 = *reinterpret_cast<const float4*>(Xs + (size_t)agr * 128 + ko + ak);
        float4 f1 = *reinterpret_cast<const float4*>(Xs + (size_t)agr * 128 + ko + ak + 4);
        // B: two 16B chunks of Wt
        const int c0 = t, c1 = t + 256;                  // chunk ids
        const int bn0 = c0 >> 2, bk0 = (c0 & 3) * 8;
        const int bn1 = c1 >> 2, bk1 = (c1 & 3) * 8;
        short8v wv0 = *reinterpret_cast<const short8v*>(Wt + (size_t)bn0 * K + k0 + bk0);
        short8v wv1 = *reinterpret_cast<const short8v*>(Wt + (size_t)bn1 * K + k0 + bk1);

        __syncthreads();   // previous iteration's consumers done

        unsigned short* ap = &Als[am * 40 + ak];
        ap[0] = f2bf(f0.x); ap[1] = f2bf(f0.y); ap[2] = f2bf(f0.z); ap[3] = f2bf(f0.w);
        ap[4] = f2bf(f1.x); ap[5] = f2bf(f1.y); ap[6] = f2bf(f1.z); ap[7] = f2bf(f1.w);
        *reinterpret_cast<short8v*>(&Bls[bn0 * 40 + bk0]) = wv0;
        *reinterpret_cast<short8v*>(&Bls[bn1 * 40 + bk1]) = wv1;

        __syncthreads();

        const short8v a = *reinterpret_cast<const short8v*>(&Als[(w * 16 + r) * 40 + kb * 8]);
#pragma unroll
        for (int c = 0; c < 8; c++) {
            const short8v b = *reinterpret_cast<const short8v*>(&Bls[(c * 16 + r) * 40 + kb * 8]);
            acc[c] = __builtin_amdgcn_mfma_f32_16x16x32_bf16(a, b, acc[c], 0, 0, 0);
        }
    }

    // epilogue: D col = c*16 + (l&15), row = w*16 + (l>>4)*4 + j
    const int col  = r;
    const int rbase = mBase + w * 16 + kb * 4;
#pragma unroll
    for (int c = 0; c < 8; c++) {
        const int gc = c * 16 + col;
        float bv = bias ? bias[gc] : 0.f;
#pragma unroll
        for (int j = 0; j < 4; j++) {
            int gr = rbase + j;
            if (gr >= M) continue;
            float v = acc[c][j] + bv;
            if (RELU)  v = fmaxf(v, 0.f);
            if (RESID) v += resid[(size_t)gr * 128 + gc];
            C[(size_t)gr * 128 + gc] = v;
        }
    }
}

__global__ __launch_bounds__(THREADS)
void zero_i32(int* __restrict__ p, int n)
{
    int i = blockIdx.x * blockDim.x + threadIdx.x;
    int stride = gridDim.x * blockDim.x;
    for (; i < n; i += stride) p[i] = 0;
}

// ---------------- CSR build (once per call; graph is layer-invariant) -------

__global__ __launch_bounds__(THREADS)
void csr_hist(const int* __restrict__ edst, int* __restrict__ deg, int nE)
{
    int i = blockIdx.x * blockDim.x + threadIdx.x;
    int stride = gridDim.x * blockDim.x;
    for (; i < nE; i += stride) atomicAdd(&deg[edst[i]], 1);
}

__global__ __launch_bounds__(THREADS)
void scan_stage1(const int* __restrict__ deg, int* __restrict__ incl,
                 int* __restrict__ psum, int n)
{
    __shared__ int buf[THREADS];
    const int t = threadIdx.x;
    const int base = blockIdx.x * 1024 + t * 4;

    int v0 = (base + 0 < n) ? deg[base + 0] : 0;
    int v1 = (base + 1 < n) ? deg[base + 1] : 0;
    int v2 = (base + 2 < n) ? deg[base + 2] : 0;
    int v3 = (base + 3 < n) ? deg[base + 3] : 0;
    const int s = v0 + v1 + v2 + v3;

    buf[t] = s;
    __syncthreads();
#pragma unroll
    for (int off = 1; off < THREADS; off <<= 1) {
        int x = (t >= off) ? buf[t - off] : 0;
        __syncthreads();
        buf[t] += x;
        __syncthreads();
    }
    const int excl = buf[t] - s;

    if (base + 0 < n) incl[base + 0] = excl + v0;
    if (base + 1 < n) incl[base + 1] = excl + v0 + v1;
    if (base + 2 < n) incl[base + 2] = excl + v0 + v1 + v2;
    if (base + 3 < n) incl[base + 3] = excl + s;
    if (t == THREADS - 1) psum[blockIdx.x] = buf[THREADS - 1];
}

__global__ __launch_bounds__(THREADS)
void scan_stage2(int* __restrict__ psum, int nb)
{
    __shared__ int buf[THREADS];
    const int t = threadIdx.x;
    int v = (t < nb) ? psum[t] : 0;
    buf[t] = v;
    __syncthreads();
#pragma unroll
    for (int off = 1; off < THREADS; off <<= 1) {
        int x = (t >= off) ? buf[t - off] : 0;
        __syncthreads();
        buf[t] += x;
        __syncthreads();
    }
    if (t < nb) psum[t] = buf[t] - v;   // exclusive
}

__global__ __launch_bounds__(THREADS)
void scan_stage3(const int* __restrict__ incl, const int* __restrict__ deg,
                 const int* __restrict__ psum, int* __restrict__ rowptr,
                 int* __restrict__ wp, int n, int nE)
{
    int i = blockIdx.x * blockDim.x + threadIdx.x;
    int stride = gridDim.x * blockDim.x;
    for (; i < n; i += stride) {
        int ex = incl[i] - deg[i] + psum[i >> 10];
        rowptr[i] = ex;
        wp[i]     = ex;
    }
    if (blockIdx.x == 0 && threadIdx.x == 0) rowptr[n] = nE;
}

__global__ __launch_bounds__(THREADS)
void csr_scatter(const int* __restrict__ esrc, const int* __restrict__ edst,
                 const float* __restrict__ eattr, int* __restrict__ wp,
                 int* __restrict__ col, float* __restrict__ eattrp, int nE)
{
    int i = blockIdx.x * blockDim.x + threadIdx.x;
    int stride = gridDim.x * blockDim.x;
    for (; i < nE; i += stride) {
        int d = edst[i];
        int pos = atomicAdd(&wp[d], 1);
        col[pos] = esrc[i];
        const float4* src4 = reinterpret_cast<const float4*>(eattr + (size_t)i * 16);
        float4*       dst4 = reinterpret_cast<float4*>(eattrp + (size_t)pos * 16);
        dst4[0] = src4[0]; dst4[1] = src4[1]; dst4[2] = src4[2]; dst4[3] = src4[3];
    }
}

// ---------------- edge aggregation: one wave per dst node -------------------
__global__ __launch_bounds__(THREADS)
void edge_agg(const float* __restrict__ A, const float* __restrict__ Bb,
              const float* __restrict__ eattrp, const int* __restrict__ col,
              const int* __restrict__ rowptr, const float* __restrict__ Wm3,
              float* __restrict__ agg, int nN)
{
    __shared__ float W3s[16 * 128];
    const int t = threadIdx.x;

    *reinterpret_cast<float4*>(&W3s[t * 4])        = *reinterpret_cast<const float4*>(Wm3 + t * 4);
    *reinterpret_cast<float4*>(&W3s[1024 + t * 4]) = *reinterpret_cast<const float4*>(Wm3 + 1024 + t * 4);
    __syncthreads();

    const int lane = t & 63;
    const int wid  = __builtin_amdgcn_readfirstlane(t >> 6);
    const int d    = blockIdx.x * 4 + wid;
    if (d >= nN) return;

    float2 w[16];
#pragma unroll
    for (int k = 0; k < 16; k++)
        w[k] = *reinterpret_cast<const float2*>(&W3s[k * 128 + lane * 2]);

    const float2 b2 = *reinterpret_cast<const float2*>(Bb + (size_t)d * 128 + lane * 2);
    float2 acc = make_float2(0.f, 0.f);

    const int beg = rowptr[d], end = rowptr[d + 1];
    for (int e = beg; e < end; e++) {
        const int s = col[e];
        const float2 a2 = *reinterpret_cast<const float2*>(A + (size_t)s * 128 + lane * 2);
        float vx = a2.x + b2.x;
        float vy = a2.y + b2.y;
        const float4* ea4 = reinterpret_cast<const float4*>(eattrp + (size_t)e * 16);
        const float4 e0 = ea4[0], e1 = ea4[1], e2 = ea4[2], e3 = ea4[3];
        const float ek[16] = {e0.x, e0.y, e0.z, e0.w, e1.x, e1.y, e1.z, e1.w,
                              e2.x, e2.y, e2.z, e2.w, e3.x, e3.y, e3.z, e3.w};
#pragma unroll
        for (int k = 0; k < 16; k++) {
            vx = fmaf(ek[k], w[k].x, vx);
            vy = fmaf(ek[k], w[k].y, vy);
        }
        acc.x += fmaxf(vx, 0.f);
        acc.y += fmaxf(vy, 0.f);
    }
    *reinterpret_cast<float2*>(agg + (size_t)d * 128 + lane * 2) = acc;
}

// ---------------- pooling: 2-stage (partial sums -> predict) ----------------

__global__ __launch_bounds__(THREADS)
void pool_partial(const float* __restrict__ h, const int* __restrict__ batch,
                  float* __restrict__ hgsum, int n)
{
    const int t    = threadIdx.x;
    const int c    = t & 127;
    const int half = t >> 7;
    const int beg  = blockIdx.x * 256;
    const int end  = min(beg + 256, n);
    if (beg >= n) return;

    int   cur = -1;
    float acc = 0.f;
    for (int r = beg + half; r < end; r += 2) {
        int g = batch[r];
        if (g != cur) {
            if (cur >= 0) atomicAdd(&hgsum[(size_t)cur * 128 + c], acc);
            cur = g; acc = 0.f;
        }
        acc += h[(size_t)r * 128 + c];
    }
    if (cur >= 0) atomicAdd(&hgsum[(size_t)cur * 128 + c], acc);
}

__global__ __launch_bounds__(THREADS)
void pool_final(const float* __restrict__ hgsum, const int* __restrict__ batch,
                const float* __restrict__ Wp, const float* __restrict__ bp,
                float* __restrict__ out, int n)
{
    __shared__ float red[128];
    const int g = blockIdx.x;
    const int t = threadIdx.x;
    if (t >= 128) return;

    int lo, hi;
    {
        int a = 0, b = n;
        while (a < b) { int m = (a + b) >> 1; if (batch[m] < g) a = m + 1; else b = m; }
        lo = a;
        b = n;
        while (a < b) { int m = (a + b) >> 1; if (batch[m] < g + 1) a = m + 1; else b = m; }
        hi = a;
    }
    const int cnt = hi - lo;

    float v = hgsum[(size_t)g * 128 + t] / (float)max(cnt, 1);
    red[t] = v * Wp[t];
    __syncthreads();
    for (int off = 64; off > 0; off >>= 1) {
        if (t < off) red[t] += red[t + off];
        __syncthreads();
    }
    if (t == 0) out[g] = red[0] + bp[0];
}

extern "C" void kernel_launch(void* const* d_in, const int* in_sizes, int n_in,
                              void* d_out, int out_size, void* d_ws, size_t ws_size,
                              hipStream_t stream)
{
    const float* x      = (const float*)d_in[0];
    const int*   ei     = (const int*)  d_in[1];
    const float* eattr  = (const float*)d_in[2];
    const int*   batch  = (const int*)  d_in[3];
    const float* W_in   = (const float*)d_in[4];
    const float* b_in   = (const float*)d_in[5];
    const float* W_msg  = (const float*)d_in[6];
    const float* b_msg  = (const float*)d_in[7];
    const float* W_upd  = (const float*)d_in[8];
    const float* b_upd  = (const float*)d_in[9];
    const float* W_pred = (const float*)d_in[10];
    const float* b_pred = (const float*)d_in[11];
    float* out = (float*)d_out;

    const int nN = in_sizes[0] / 128;   // 50000
    const int nE = in_sizes[1] / 2;     // 800000
    const int* esrc = ei;
    const int* edst = ei + nE;

    // workspace carve-up
    float* h      = (float*)d_ws;
    float* A      = h      + (size_t)nN * 128;
    float* Bb     = A      + (size_t)nN * 128;
    float* agg    = Bb     + (size_t)nN * 128;
    float* eattrp = agg    + (size_t)nN * 128;
    float* hgsum  = eattrp + (size_t)nE * 16;
    int*   rowptr = (int*)(hgsum + 64 * 128);
    int*   wp     = rowptr + (nN + 1);
    int*   deg    = wp     + nN;
    int*   incl   = deg    + nN;
    int*   psum   = incl   + nN;
    int*   col    = psum   + 256;
    // bf16 weights, 64B-aligned
    size_t wboff = ((size_t)(col + nE) - (size_t)d_ws + 63) & ~(size_t)63;
    unsigned short* wbf = (unsigned short*)((char*)d_ws + wboff);
    unsigned short* wt_in  = wbf;                 // [128][128]
    unsigned short* wt_m1  = wbf + 16384;         // 4 x [128][128]
    unsigned short* wt_m2  = wbf + 81920;         // 4 x [128][128]
    unsigned short* wt_up  = wbf + 147456;        // 4 x [128][256]

    dim3 blk(THREADS);
    const int gx = (nN + 63) / 64;
    const int nChunks = (nN + 1023) / 1024;   // 49

    // ---- weights -> bf16 [n][k] (once) ----
    wconv_all<<<1088, blk, 0, stream>>>(W_in, W_msg, W_upd, wbf);

    // ---- CSR build (graph constant across layers) ----
    zero_i32<<<64, blk, 0, stream>>>(deg, nN);
    csr_hist<<<256, blk, 0, stream>>>(edst, deg, nE);
    scan_stage1<<<nChunks, blk, 0, stream>>>(deg, incl, psum, nN);
    scan_stage2<<<1, blk, 0, stream>>>(psum, nChunks);
    scan_stage3<<<64, blk, 0, stream>>>(incl, deg, psum, rowptr, wp, nN, nE);
    csr_scatter<<<256, blk, 0, stream>>>(esrc, edst, eattr, wp, col, eattrp, nE);

    // h = x @ W_in + b_in
    gemm_bf16<false, false><<<gx, blk, 0, stream>>>(x, nullptr, wt_in, b_in, nullptr, h, nN, 128);

    for (int l = 0; l < 4; l++) {
        const float* Wm3 = W_msg + (size_t)l * 272 * 128 + 256 * 128;
        const float* bm  = b_msg + l * 128;
        const float* bu  = b_upd + l * 128;

        gemm_bf16<false, false><<<gx, blk, 0, stream>>>(h, nullptr, wt_m1 + l * 16384, nullptr, nullptr, A,  nN, 128);
        gemm_bf16<false, false><<<gx, blk, 0, stream>>>(h, nullptr, wt_m2 + l * 16384, bm,      nullptr, Bb, nN, 128);

        edge_agg<<<(nN + 3) / 4, blk, 0, stream>>>(A, Bb, eattrp, col, rowptr, Wm3, agg, nN);

        gemm_bf16<true, true><<<gx, blk, 0, stream>>>(h, agg, wt_up + l * 32768, bu, h, h, nN, 256);
    }

    // ---- 2-stage mean pool + predict ----
    zero_i32<<<16, blk, 0, stream>>>((int*)hgsum, 64 * 128);
    pool_partial<<<(nN + 255) / 256, blk, 0, stream>>>(h, batch, hgsum, nN);
    pool_final<<<64, blk, 0, stream>>>(hgsum, batch, W_pred, b_pred, out, nN);
}